// Round 2
// baseline (50269.568 us; speedup 1.0000x reference)
//
#include <hip/hip_runtime.h>
#include <hip/hip_bf16.h>

static constexpr int Bsz  = 256;   // batch
static constexpr int Tseq = 256;   // timesteps
static constexpr int Hd   = 512;   // d_model
static constexpr int Ein  = 64;    // enc_in

// Per-step pointer bundle (state rotates across steps; weights passed per-launch).
struct Params {
  const float* x;                     // [B, T, Ein] fp32
  float *Hm1, *Hm2, *Hcur, *Nst;      // h_{t-1}, h_{t-2}, h_t, N (fp32 state)
  float *zA, *NrA, *s1, *score, *Omega, *mbuf, *zM, *mrM;  // per-step scratch
  float* out_hidden;                  // [B, T, Hd] fp32
  int t;
};

__device__ __forceinline__ float sigm(float x) { return 1.f / (1.f + expf(-x)); }

enum { A_DT, A_WS, A_X };   // A-operand source: (Hm1-Hm2) diff, fp32 ws buffer, x_t
enum { E_GATEA, E_NNEW, E_S1, E_SCORE, E_M, E_GATEM, E_HNEW };

// Generic dual-GEMM: C = A1@W1 [+ A2@W2] (+bias) with fused per-phase epilogue.
// M=256 fixed. Tile 32x32, 256 threads, 2x2 acc/thread, TK=32 chunks.
// A1 pass: K1 contraction; A2 pass: K2 (0 = skipped). W row-major [K, NC] fp32.
template<int A1M, int K1, int K2, int NC, int EPI>
__global__ __launch_bounds__(256)
void gemm_step(Params p,
               const float* __restrict__ W1, const float* __restrict__ W2,
               const float* __restrict__ bias,
               const float* __restrict__ A1, const float* __restrict__ A1b,
               const float* __restrict__ A2)
{
  __shared__ float Ast[32][34];  // [k][m], +2 pad keeps float2 reads 8B-aligned
  __shared__ float Wst[32][34];  // [k][n]
  const int tid = threadIdx.x;
  const int mb = blockIdx.y * 32;
  const int nb = blockIdx.x * 32;
  const int tx = tid & 15, ty = tid >> 4;
  const int lr = tid >> 3;          // staging row (A) / k (W), 0..31
  const int lc = (tid & 7) << 2;    // staging 4-wide column base

  float acc00 = 0.f, acc01 = 0.f, acc10 = 0.f, acc11 = 0.f;

  #pragma unroll
  for (int pass = 0; pass < 2; ++pass) {
    const int KT = pass ? K2 : K1;
    const float* W = pass ? W2 : W1;
    for (int kb = 0; kb < KT; kb += 32) {
      float a0, a1, a2, a3;
      if (pass == 0 && A1M == A_X) {
        const float4 u = *(const float4*)(p.x + (size_t)(mb + lr) * (Tseq * Ein) + p.t * Ein + kb + lc);
        a0 = u.x; a1 = u.y; a2 = u.z; a3 = u.w;
      } else if (pass == 0 && A1M == A_DT) {
        const float4 u = *(const float4*)(A1 + (mb + lr) * Hd + kb + lc);
        const float4 v = *(const float4*)(A1b + (mb + lr) * Hd + kb + lc);
        a0 = u.x - v.x; a1 = u.y - v.y; a2 = u.z - v.z; a3 = u.w - v.w;
      } else {
        const float* A = pass ? A2 : A1;
        const float4 u = *(const float4*)(A + (mb + lr) * Hd + kb + lc);
        a0 = u.x; a1 = u.y; a2 = u.z; a3 = u.w;
      }
      Ast[lc + 0][lr] = a0; Ast[lc + 1][lr] = a1;
      Ast[lc + 2][lr] = a2; Ast[lc + 3][lr] = a3;

      const float4 w4 = *(const float4*)(W + (size_t)(kb + lr) * NC + nb + lc);
      Wst[lr][lc + 0] = w4.x; Wst[lr][lc + 1] = w4.y;
      Wst[lr][lc + 2] = w4.z; Wst[lr][lc + 3] = w4.w;

      __syncthreads();
      #pragma unroll
      for (int kk = 0; kk < 32; ++kk) {
        const float2 av = *(const float2*)&Ast[kk][ty << 1];
        const float2 bv = *(const float2*)&Wst[kk][tx << 1];
        acc00 += av.x * bv.x; acc01 += av.x * bv.y;
        acc10 += av.y * bv.x; acc11 += av.y * bv.y;
      }
      __syncthreads();
    }
  }

  const float accs[2][2] = {{acc00, acc01}, {acc10, acc11}};
  #pragma unroll
  for (int r = 0; r < 2; ++r) {
    const int row = mb + (ty << 1) + r;
    #pragma unroll
    for (int c = 0; c < 2; ++c) {
      const int col = nb + (tx << 1) + c;
      float g = accs[r][c];
      if (bias) g += bias[col];
      if constexpr (EPI == E_GATEA) {            // gates_A -> z_A, N*r_A
        const float s = sigm(g);
        if (col < Hd) p.zA[row * Hd + col] = s;
        else { const int j = col - Hd; p.NrA[row * Hd + j] = p.Nst[row * Hd + j] * s; }
      } else if constexpr (EPI == E_NNEW) {      // hat_N -> N_new (in-place, col-local)
        const float hn = tanhf(g);
        const float z  = p.zA[row * Hd + col];
        const float No = p.Nst[row * Hd + col];
        p.Nst[row * Hd + col] = (1.f - z) * No + z * hn;
      } else if constexpr (EPI == E_S1) {        // tanh(h@WAttn + N_new@UAttn)
        p.s1[row * Hd + col] = tanhf(g);
      } else if constexpr (EPI == E_SCORE) {     // s1 @ VAttn (pre-softmax)
        p.score[row * Hd + col] = g;
      } else if constexpr (EPI == E_M) {         // m = tanh(Omega@Wma + h@Uma + bma)
        p.mbuf[row * Hd + col] = tanhf(g);
      } else if constexpr (EPI == E_GATEM) {     // gates_M -> z_M, m*r_M
        const float s = sigm(g);
        if (col < Hd) p.zM[row * Hd + col] = s;
        else { const int j = col - Hd; p.mrM[row * Hd + j] = p.mbuf[row * Hd + j] * s; }
      } else if constexpr (EPI == E_HNEW) {      // hat_h -> h_new, write output
        const float hh = tanhf(g);
        const float z  = p.zM[row * Hd + col];
        const float hp = p.Hm1[row * Hd + col];
        const float hnew = (1.f - z) * hp + z * hh;
        p.Hcur[row * Hd + col] = hnew;
        p.out_hidden[((size_t)row * Tseq + p.t) * Hd + col] = hnew;
      }
    }
  }
}

// One block per batch row: softmax over Hd=512, Omega = alpha * N_new.
__global__ __launch_bounds__(256)
void softmax_omega(Params p)
{
  __shared__ float red[256];
  const int b = blockIdx.x, tid = threadIdx.x;
  const float* sc = p.score + b * Hd;
  const float v0 = sc[tid], v1 = sc[tid + 256];
  red[tid] = fmaxf(v0, v1);
  __syncthreads();
  for (int s = 128; s > 0; s >>= 1) {
    if (tid < s) red[tid] = fmaxf(red[tid], red[tid + s]);
    __syncthreads();
  }
  const float mx = red[0];
  __syncthreads();
  const float e0 = expf(v0 - mx), e1 = expf(v1 - mx);
  red[tid] = e0 + e1;
  __syncthreads();
  for (int s = 128; s > 0; s >>= 1) {
    if (tid < s) red[tid] += red[tid + s];
    __syncthreads();
  }
  const float inv = 1.f / red[0];
  p.Omega[b * Hd + tid]       = e0 * inv * p.Nst[b * Hd + tid];
  p.Omega[b * Hd + tid + 256] = e1 * inv * p.Nst[b * Hd + tid + 256];
}

__global__ __launch_bounds__(256)
void init_state(float* h1, float* h2, float* n) {
  const int i = blockIdx.x * 256 + threadIdx.x;
  h1[i] = 0.f; h2[i] = 0.f; n[i] = 0.f;
}

__global__ __launch_bounds__(256)
void finalize(const float* __restrict__ hT, const float* __restrict__ nT,
              float* __restrict__ oh, float* __restrict__ on) {
  const int i = blockIdx.x * 256 + threadIdx.x;
  oh[i] = hT[i]; on[i] = nT[i];
}

extern "C" void kernel_launch(void* const* d_in, const int* in_sizes, int n_in,
                              void* d_out, int out_size, void* d_ws, size_t ws_size,
                              hipStream_t stream)
{
  (void)in_sizes; (void)n_in; (void)out_size; (void)ws_size;
  const float* x   = (const float*)d_in[0];
  const float* Wa  = (const float*)d_in[1];
  const float* Ua  = (const float*)d_in[2];
  const float* ba  = (const float*)d_in[3];
  const float* Wna = (const float*)d_in[4];
  const float* Una = (const float*)d_in[5];
  const float* bna = (const float*)d_in[6];
  const float* WAt = (const float*)d_in[7];
  const float* UAt = (const float*)d_in[8];
  const float* VAt = (const float*)d_in[9];
  const float* Wma = (const float*)d_in[10];
  const float* Uma = (const float*)d_in[11];
  const float* bma = (const float*)d_in[12];
  const float* Wm  = (const float*)d_in[13];
  const float* Um  = (const float*)d_in[14];
  const float* bm  = (const float*)d_in[15];
  const float* Whm = (const float*)d_in[16];
  const float* Uhm = (const float*)d_in[17];
  const float* bhm = (const float*)d_in[18];

  float* w = (float*)d_ws;
  const int S = Bsz * Hd;               // 131072 floats per state buffer
  float* Hb[3] = { w, w + S, w + 2 * S };

  Params p{};
  p.x = x;
  p.Nst = w + 3 * S;  p.zA = w + 4 * S;  p.NrA = w + 5 * S;  p.s1 = w + 6 * S;
  p.score = w + 7 * S; p.Omega = w + 8 * S; p.mbuf = w + 9 * S;
  p.zM = w + 10 * S;  p.mrM = w + 11 * S;           // total ws use: 6.3 MB fp32
  float* out = (float*)d_out;
  p.out_hidden = out;
  float* out_hT = out + (size_t)Bsz * Tseq * Hd;
  float* out_NT = out_hT + S;

  init_state<<<S / 256, 256, 0, stream>>>(Hb[1], Hb[2], p.Nst);

  const dim3 blk(256);
  const dim3 g512(Hd / 32, Bsz / 32);        // 16 x 8 = 128 blocks
  const dim3 g1024(2 * Hd / 32, Bsz / 32);   // 32 x 8 = 256 blocks

  for (int t = 0; t < Tseq; ++t) {
    Params q = p;
    q.t = t;
    q.Hcur = Hb[t % 3];          // h_t
    q.Hm1  = Hb[(t + 2) % 3];    // h_{t-1}
    q.Hm2  = Hb[(t + 1) % 3];    // h_{t-2}
    // gates_A = d_t@Wa + N@Ua + ba -> z_A, NrA
    gemm_step<A_DT, 512, 512, 1024, E_GATEA><<<g1024, blk, 0, stream>>>(q, Wa, Ua, ba, q.Hm1, q.Hm2, q.Nst);
    // hat_N = tanh(d_t@Wna + NrA@Una + bna); N <- (1-z)N + z hat_N
    gemm_step<A_DT, 512, 512, 512,  E_NNEW ><<<g512,  blk, 0, stream>>>(q, Wna, Una, bna, q.Hm1, q.Hm2, q.NrA);
    // s1 = tanh(h@WAttn + N_new@UAttn)
    gemm_step<A_WS, 512, 512, 512,  E_S1   ><<<g512,  blk, 0, stream>>>(q, WAt, UAt, nullptr, q.Hm1, nullptr, q.Nst);
    // score = s1 @ VAttn
    gemm_step<A_WS, 512, 0,   512,  E_SCORE><<<g512,  blk, 0, stream>>>(q, VAt, nullptr, nullptr, q.s1, nullptr, nullptr);
    // alpha = softmax(score); Omega = alpha * N_new
    softmax_omega<<<Bsz, blk, 0, stream>>>(q);
    // m = tanh(Omega@Wma + h@Uma + bma)
    gemm_step<A_WS, 512, 512, 512,  E_M    ><<<g512,  blk, 0, stream>>>(q, Wma, Uma, bma, q.Omega, nullptr, q.Hm1);
    // gates_M = x_t@Wm + m@Um + bm -> z_M, mrM
    gemm_step<A_X,  64,  512, 1024, E_GATEM><<<g1024, blk, 0, stream>>>(q, Wm, Um, bm, nullptr, nullptr, q.mbuf);
    // hat_h = tanh(x_t@Whm + mrM@Uhm + bhm); h_t = (1-z_M)h + z_M hat_h; emit output
    gemm_step<A_X,  64,  512, 512,  E_HNEW ><<<g512,  blk, 0, stream>>>(q, Whm, Uhm, bhm, nullptr, nullptr, q.mrM);
  }
  finalize<<<S / 256, 256, 0, stream>>>(Hb[(Tseq - 1) % 3], p.Nst, out_hT, out_NT);
}